// Round 7
// baseline (60.903 us; speedup 1.0000x reference)
//
#include <hip/hip_runtime.h>
#include <hip/hip_bf16.h>

#define FEATS 512
#define NW 5
#define NH 16
#define NOUT 5
#define HPB 2                      // heads per block
#define NBLK (FEATS / HPB)         // 256 blocks -> 1 per CU

// ws (floats): [0,512) x_orig | [512,1024) x_sorted
// acc: 2560 slots PADDED to one fp32 per 64B line (stride 16 floats) -> spreads
// MALL banks/channels; contiguous 10KB hot set was serializing at a few banks.
#define ACC_OFF 1024
#define ACC_STRIDE 16
#define CNT_OFF (ACC_OFF + FEATS * NOUT * ACC_STRIDE)
#define WS_FLOATS_NEEDED (CNT_OFF + 1)

// ---------------- Kernel A: window-sum + parallel rank sort + zero acc (64 blocks) ----
__global__ __launch_bounds__(512) void prep_sort(const float* __restrict__ data,
                                                 float* __restrict__ ws) {
    __shared__ float xs[FEATS];
    const int t = threadIdx.x;
    float v = 0.f;
    #pragma unroll
    for (int w = 0; w < NW; ++w) v += data[w * FEATS + t];
    xs[t] = v;
    __syncthreads();

    const int wid = t >> 6, lane = t & 63;
    const int i = blockIdx.x * 8 + wid;
    const float vi = xs[i];               // wave-uniform -> LDS broadcast
    int r = 0;
    #pragma unroll
    for (int u = 0; u < 8; ++u) {
        const int j = u * 64 + lane;
        const float xj = xs[j];
        r += (xj < vi) || (xj == vi && j < i);   // stable -> rank is a permutation
    }
    #pragma unroll
    for (int off = 32; off; off >>= 1) r += __shfl_xor(r, off);
    if (lane == 0) ws[FEATS + r] = vi;    // x_sorted ascending
    if (blockIdx.x == 0) ws[t] = xs[t];   // x_orig

    // zero the PADDED acc slots + ticket every launch (harness poisons ws once
    // with 0xAA; graph replays must start from zero)
    const int g = blockIdx.x * 512 + t;
    if (g < FEATS * NOUT) ws[ACC_OFF + g * ACC_STRIDE] = 0.f;
    if (g == FEATS * NOUT) ws[CNT_OFF] = 0.f;
}

// ---------------- Kernel B: GAT heads + collapsed MLP + ticket finalize (256 blocks) --
// leaky(.,1.0)==identity => fcn is affine: out = sigmoid(feat_r @ (F2@F1)^T + F2@fb1+fb2).
// Per head: shfl-scan prefix tables over sorted x (SoA in LDS), binary-search epilogue
// per dst i, project onto G[:,h]=F2@F1[:,h], pre-reduce HPB heads in registers, then ONE
// native fp32 no-return atomic per (o,i) into the bank-padded acc. s_waitcnt vmcnt(0)
// completes my adds before the RELAXED ticket RMW issues (no wbl2/inv maintenance).
__global__ __launch_bounds__(512) void gat_mlp(
    float* __restrict__ ws,
    const float* __restrict__ gat_w, const float* __restrict__ a_src,
    const float* __restrict__ a_dst, const float* __restrict__ gat_bias,
    const float* __restrict__ F1, const float* __restrict__ fb1,
    const float* __restrict__ F2, const float* __restrict__ fb2,
    float* __restrict__ out)
{
    __shared__ float xsrt[FEATS];
    __shared__ float preX[FEATS + 1], preY[FEATS + 1], preZ[FEATS + 1], preW[FEATS + 1];
    __shared__ float4 wtot[8];
    __shared__ int amLast;

    const int t = threadIdx.x;
    const int lane = t & 63, wid = t >> 6;
    const float LOG2E = 1.4426950408889634f;

    const float xv = ws[FEATS + t];       // sorted x
    const float xi = ws[t];               // original x (dst term), thread t = dst i
    xsrt[t] = xv;

    float accv[NOUT] = {0.f, 0.f, 0.f, 0.f, 0.f};

    #pragma unroll
    for (int hh = 0; hh < HPB; ++hh) {
        const int h = blockIdx.x * HPB + hh;
        const float gwv = gat_w[h];
        const float cs  = gwv * a_src[h] * LOG2E;
        const float cd  = gwv * a_dst[h] * LOG2E;

        const float p1 = __builtin_amdgcn_exp2f(cs * xv);
        const float p2 = __builtin_amdgcn_exp2f(0.2f * cs * xv);
        float4 s = make_float4(p1, p2, xv * p1, xv * p2);

        // 64-lane inclusive scan, register-only
        #pragma unroll
        for (int d = 1; d < 64; d <<= 1) {
            const float ax = __shfl_up(s.x, d);
            const float ay = __shfl_up(s.y, d);
            const float az = __shfl_up(s.z, d);
            const float aw = __shfl_up(s.w, d);
            if (lane >= d) { s.x += ax; s.y += ay; s.z += az; s.w += aw; }
        }
        if (lane == 63) wtot[wid] = s;
        __syncthreads();
        float4 o4 = make_float4(0.f, 0.f, 0.f, 0.f);
        #pragma unroll
        for (int w = 0; w < 7; ++w) {
            if (w < wid) {
                const float4 u = wtot[w];          // wave-uniform -> broadcast
                o4.x += u.x; o4.y += u.y; o4.z += u.z; o4.w += u.w;
            }
        }
        s.x += o4.x; s.y += o4.y; s.z += o4.z; s.w += o4.w;
        // SoA exclusive prefix (stride-1 b32 writes: conflict-free)
        preX[t + 1] = s.x; preY[t + 1] = s.y; preZ[t + 1] = s.z; preW[t + 1] = s.w;
        if (t == 0) { preX[0] = 0.f; preY[0] = 0.f; preZ[0] = 0.f; preW[0] = 0.f; }
        __syncthreads();

        // epilogue for dst i = t
        const float dterm = cd * xi;
        const bool csn = (cs >= 0.f);
        int m = 0;
        #pragma unroll
        for (int step = 256; step; step >>= 1) {
            const int cand = m + step;
            const float tt = fmaf(xsrt[cand - 1], cs, dterm);
            const bool p = csn ? (tt >= 0.f) : (tt < 0.f);
            if (!p) m = cand;
        }
        const float Px = preX[m], Py = preY[m], Pz = preZ[m], Pw = preW[m];
        const float Tx = preX[FEATS], Ty = preY[FEATS], Tz = preZ[FEATS], Tw = preW[FEATS];
        const float A1 = __builtin_amdgcn_exp2f(dterm);
        const float A2 = __builtin_amdgcn_exp2f(0.2f * dterm);
        float Se, Sv;
        if (csn) {
            Se = A1 * (Tx - Px) + A2 * Py;
            Sv = A1 * (Tz - Pz) + A2 * Pw;
        } else {
            Se = A1 * Px + A2 * (Ty - Py);
            Sv = A1 * Pz + A2 * (Tw - Pw);
        }
        const float fv = gwv * (Sv / Se) + gat_bias[h];

        // project onto G[:,h] = F2 @ F1[:,h]  (h uniform per block -> scalar loads)
        #pragma unroll
        for (int o = 0; o < NOUT; ++o) {
            float g = 0.f;
            #pragma unroll
            for (int k = 0; k < NH; ++k) g = fmaf(F2[o * NH + k], F1[k * FEATS + h], g);
            accv[o] = fmaf(g, fv, accv[o]);
        }
        __syncthreads();                  // protect pre/wtot reuse by next head
    }

    float* acc = ws + ACC_OFF;
    #pragma unroll
    for (int o = 0; o < NOUT; ++o)
        unsafeAtomicAdd(&acc[(o * FEATS + t) * ACC_STRIDE], accv[o]);  // padded slot

    // my adds are performed (ack'd at the coherence point) before the ticket issues
    asm volatile("s_waitcnt vmcnt(0)" ::: "memory");
    __syncthreads();
    if (t == 0) {
        const int old = __hip_atomic_fetch_add((int*)(ws + CNT_OFF), 1,
                                               __ATOMIC_RELAXED,
                                               __HIP_MEMORY_SCOPE_AGENT);
        amLast = (old == NBLK - 1);
    }
    __syncthreads();   // compiler barrier: acc loads can't hoist above
    if (amLast) {
        float cp[NOUT];
        #pragma unroll
        for (int o = 0; o < NOUT; ++o) {
            float c = fb2[o];
            #pragma unroll
            for (int k = 0; k < NH; ++k) c = fmaf(F2[o * NH + k], fb1[k], c);
            cp[o] = c;
        }
        // relaxed agent loads (no buffer_inv): this block never normal-loaded acc,
        // and atomics don't allocate in the non-coherent L2s.
        #pragma unroll
        for (int o = 0; o < NOUT; ++o) {
            const float sval = __hip_atomic_load(&acc[(o * FEATS + t) * ACC_STRIDE],
                                                 __ATOMIC_RELAXED,
                                                 __HIP_MEMORY_SCOPE_AGENT) + cp[o];
            out[t * NOUT + o] = 1.f / (1.f + __builtin_amdgcn_exp2f(-sval * LOG2E));
        }
    }
}

// ---------------- Fallback: fused O(N^3) kernel (if ws too small) ----------------
__global__ __launch_bounds__(512) void gat_fused_fb(
    const float* __restrict__ data,
    const float* __restrict__ gat_w, const float* __restrict__ a_src,
    const float* __restrict__ a_dst, const float* __restrict__ gat_bias,
    const float* __restrict__ F1, const float* __restrict__ fb1,
    const float* __restrict__ F2, const float* __restrict__ fb2,
    float* __restrict__ out)
{
    __shared__ __align__(16) float xs[FEATS];
    __shared__ float feat[FEATS];
    __shared__ float part[NH][8];
    __shared__ float hv[NH];
    const int h = threadIdx.x;
    const int i = blockIdx.x;
    float v = 0.f;
    #pragma unroll
    for (int w = 0; w < NW; ++w) v += data[w * FEATS + h];
    xs[h] = v;
    __syncthreads();
    const float LOG2E = 1.4426950408889634f;
    const float gwv = gat_w[h];
    const float cs = gwv * a_src[h] * LOG2E;
    const float cd = gwv * a_dst[h] * LOG2E;
    const float di = xs[i] * cd;
    float se = 0.f, sv = 0.f;
    const float4* x4 = (const float4*)xs;
    for (int j4 = 0; j4 < FEATS / 4; ++j4) {
        float4 q = x4[j4];
        #pragma unroll
        for (int u = 0; u < 4; ++u) {
            float xj = (u == 0) ? q.x : (u == 1) ? q.y : (u == 2) ? q.z : q.w;
            float tt = fmaf(xj, cs, di);
            float l  = fmaxf(tt, 0.2f * tt);
            float e  = __builtin_amdgcn_exp2f(l);
            se += e;
            sv = fmaf(e, xj, sv);
        }
    }
    feat[h] = gwv * sv / se + gat_bias[h];
    __syncthreads();
    const int lane = h & 63, wid = h >> 6;
    const float fv = feat[h];
    for (int k = 0; k < NH; ++k) {
        float p = fv * F1[k * FEATS + h];
        #pragma unroll
        for (int off = 32; off; off >>= 1) p += __shfl_xor(p, off);
        if (lane == 0) part[k][wid] = p;
    }
    __syncthreads();
    if (h < NH) {
        float s = fb1[h];
        #pragma unroll
        for (int w = 0; w < 8; ++w) s += part[h][w];
        hv[h] = s;
    }
    __syncthreads();
    if (h < 5) {
        float s = fb2[h];
        #pragma unroll
        for (int k = 0; k < NH; ++k) s = fmaf(hv[k], F2[h * NH + k], s);
        out[i * 5 + h] = 1.f / (1.f + __builtin_amdgcn_exp2f(-s * LOG2E));
    }
}

extern "C" void kernel_launch(void* const* d_in, const int* in_sizes, int n_in,
                              void* d_out, int out_size, void* d_ws, size_t ws_size,
                              hipStream_t stream) {
    (void)in_sizes; (void)n_in; (void)out_size;
    const float* data     = (const float*)d_in[0];
    // d_in[1..6] = W1,b1,W2,b2,W3,b3 — dead (softmax over batch dim of size 1 == 1)
    const float* gat_w    = (const float*)d_in[7];
    const float* a_src    = (const float*)d_in[8];
    const float* a_dst    = (const float*)d_in[9];
    const float* gat_bias = (const float*)d_in[10];
    const float* F1       = (const float*)d_in[11];
    const float* fb1      = (const float*)d_in[12];
    const float* F2       = (const float*)d_in[13];
    const float* fb2      = (const float*)d_in[14];
    float* out = (float*)d_out;

    if (ws_size >= (size_t)WS_FLOATS_NEEDED * sizeof(float)) {
        float* ws = (float*)d_ws;
        prep_sort<<<64, FEATS, 0, stream>>>(data, ws);
        gat_mlp<<<NBLK, FEATS, 0, stream>>>(ws, gat_w, a_src, a_dst, gat_bias,
                                            F1, fb1, F2, fb2, out);
    } else {
        gat_fused_fb<<<FEATS, FEATS, 0, stream>>>(data, gat_w, a_src, a_dst, gat_bias,
                                                  F1, fb1, F2, fb2, out);
    }
}

// Round 8
// 27.377 us; speedup vs baseline: 2.2246x; 2.2246x over previous
//
#include <hip/hip_runtime.h>
#include <hip/hip_bf16.h>

#define FEATS 512
#define NW 5
#define NH 16
#define NOUT 5
#define HPB 2                      // heads per block (phase 1)
#define IPB 2                      // dst nodes per block (phase 2)
#define NBLK (FEATS / HPB)         // 256 blocks

// ws (floats): [0,512) x_orig | [512,1024) x_sorted | [1024] barrier cnt | [1040,+512*512) feat_t (i-major)
#define CNT_OFF 1024
#define FEAT_OFF 1040
#define WS_FLOATS_NEEDED (FEAT_OFF + FEATS * FEATS)

// ---------------- Kernel A: window-sum + parallel rank sort + zero barrier (64 blocks) -
__global__ __launch_bounds__(512) void prep_sort(const float* __restrict__ data,
                                                 float* __restrict__ ws) {
    __shared__ float xs[FEATS];
    const int t = threadIdx.x;
    float v = 0.f;
    #pragma unroll
    for (int w = 0; w < NW; ++w) v += data[w * FEATS + t];
    xs[t] = v;
    __syncthreads();

    const int wid = t >> 6, lane = t & 63;
    const int i = blockIdx.x * 8 + wid;
    const float vi = xs[i];               // wave-uniform -> LDS broadcast
    int r = 0;
    #pragma unroll
    for (int u = 0; u < 8; ++u) {
        const int j = u * 64 + lane;
        const float xj = xs[j];
        r += (xj < vi) || (xj == vi && j < i);   // stable -> rank is a permutation
    }
    #pragma unroll
    for (int off = 32; off; off >>= 1) r += __shfl_xor(r, off);
    if (lane == 0) ws[FEATS + r] = vi;    // x_sorted ascending
    if (blockIdx.x == 0) ws[t] = xs[t];   // x_orig
    // zero the grid-barrier counter EVERY launch (ws is poisoned 0xAA once
    // before timing; dispatch-boundary release makes this visible to kernel B)
    if (blockIdx.x == 1 && t == 0) *(int*)(ws + CNT_OFF) = 0;
}

// ---------------- Kernel B: GAT heads -> grid barrier -> collapsed MLP (256 blocks) ----
// Phase 1 (block b = heads 2b,2b+1): shfl-scan prefix tables over sorted x, binary-search
// epilogue per dst i, feat values stored as ONE 8B relaxed agent (MALL-direct) store per
// thread. Barrier: vmcnt(0) -> one relaxed fetch_add per block -> t0 spins (all 256
// blocks are resident by capacity: >=4 blocks/CU fit, so no deadlock). Phase 2 (block b
// = dst nodes 2b,2b+1): coalesced relaxed loads of feat rows, out = sigmoid(G@feat+c),
// G = F2@F1 precomputed in registers during the barrier wait.
__global__ __launch_bounds__(512) void gat_barrier(
    float* __restrict__ ws,
    const float* __restrict__ gat_w, const float* __restrict__ a_src,
    const float* __restrict__ a_dst, const float* __restrict__ gat_bias,
    const float* __restrict__ F1, const float* __restrict__ fb1,
    const float* __restrict__ F2, const float* __restrict__ fb2,
    float* __restrict__ out)
{
    __shared__ float xsrt[FEATS];
    __shared__ float preX[FEATS + 1], preY[FEATS + 1], preZ[FEATS + 1], preW[FEATS + 1];
    __shared__ float4 wtot[8];
    __shared__ float part[NOUT][8];

    const int t = threadIdx.x;
    const int lane = t & 63, wid = t >> 6;
    const float LOG2E = 1.4426950408889634f;

    const float xv = ws[FEATS + t];       // sorted x
    const float xi = ws[t];               // original x (dst term), thread t = dst i
    xsrt[t] = xv;

    float fv2[HPB];

    #pragma unroll
    for (int hh = 0; hh < HPB; ++hh) {
        const int h = blockIdx.x * HPB + hh;
        const float gwv = gat_w[h];
        const float cs  = gwv * a_src[h] * LOG2E;
        const float cd  = gwv * a_dst[h] * LOG2E;

        const float p1 = __builtin_amdgcn_exp2f(cs * xv);
        const float p2 = __builtin_amdgcn_exp2f(0.2f * cs * xv);
        float4 s = make_float4(p1, p2, xv * p1, xv * p2);

        // 64-lane inclusive scan, register-only
        #pragma unroll
        for (int d = 1; d < 64; d <<= 1) {
            const float ax = __shfl_up(s.x, d);
            const float ay = __shfl_up(s.y, d);
            const float az = __shfl_up(s.z, d);
            const float aw = __shfl_up(s.w, d);
            if (lane >= d) { s.x += ax; s.y += ay; s.z += az; s.w += aw; }
        }
        if (lane == 63) wtot[wid] = s;
        __syncthreads();
        float4 o4 = make_float4(0.f, 0.f, 0.f, 0.f);
        #pragma unroll
        for (int w = 0; w < 7; ++w) {
            if (w < wid) {
                const float4 u = wtot[w];          // wave-uniform -> broadcast
                o4.x += u.x; o4.y += u.y; o4.z += u.z; o4.w += u.w;
            }
        }
        s.x += o4.x; s.y += o4.y; s.z += o4.z; s.w += o4.w;
        preX[t + 1] = s.x; preY[t + 1] = s.y; preZ[t + 1] = s.z; preW[t + 1] = s.w;
        if (t == 0) { preX[0] = 0.f; preY[0] = 0.f; preZ[0] = 0.f; preW[0] = 0.f; }
        __syncthreads();

        // epilogue for dst i = t
        const float dterm = cd * xi;
        const bool csn = (cs >= 0.f);
        int m = 0;
        #pragma unroll
        for (int step = 256; step; step >>= 1) {
            const int cand = m + step;
            const float tt = fmaf(xsrt[cand - 1], cs, dterm);
            const bool p = csn ? (tt >= 0.f) : (tt < 0.f);
            if (!p) m = cand;
        }
        const float Px = preX[m], Py = preY[m], Pz = preZ[m], Pw = preW[m];
        const float Tx = preX[FEATS], Ty = preY[FEATS], Tz = preZ[FEATS], Tw = preW[FEATS];
        const float A1 = __builtin_amdgcn_exp2f(dterm);
        const float A2 = __builtin_amdgcn_exp2f(0.2f * dterm);
        float Se, Sv;
        if (csn) {
            Se = A1 * (Tx - Px) + A2 * Py;
            Sv = A1 * (Tz - Pz) + A2 * Pw;
        } else {
            Se = A1 * Px + A2 * (Ty - Py);
            Sv = A1 * Pz + A2 * (Tw - Pw);
        }
        fv2[hh] = gwv * (Sv / Se) + gat_bias[h];
        __syncthreads();                  // protect pre/wtot reuse by next head
    }

    // one 8B MALL-direct store: feat_t[i=t][h0..h0+1]  (addr 8B-aligned: h0 even)
    float* feat_t = ws + FEAT_OFF;
    {
        union { float f[2]; unsigned long long u; } pk;
        pk.f[0] = fv2[0]; pk.f[1] = fv2[1];
        unsigned long long* dst =
            (unsigned long long*)(feat_t + t * FEATS + blockIdx.x * HPB);
        __hip_atomic_store(dst, pk.u, __ATOMIC_RELAXED, __HIP_MEMORY_SCOPE_AGENT);
    }

    // ---- overlap: G[o] = F2[o,:] @ F1[:,t]  and  c[o] = F2@fb1+fb2 (registers)
    float G[NOUT], cst[NOUT];
    #pragma unroll
    for (int o = 0; o < NOUT; ++o) {
        float g = 0.f, c = fb2[o];
        #pragma unroll
        for (int k = 0; k < NH; ++k) {
            const float f2 = F2[o * NH + k];
            g = fmaf(f2, F1[k * FEATS + t], g);
            c = fmaf(f2, fb1[k], c);
        }
        G[o] = g; cst[o] = c;
    }

    // ---- grid barrier (relaxed, MALL-resident; no L2 maintenance ops)
    asm volatile("s_waitcnt vmcnt(0)" ::: "memory");   // my stores performed at MALL
    __syncthreads();
    int* cnt = (int*)(ws + CNT_OFF);
    if (t == 0) {
        __hip_atomic_fetch_add(cnt, 1, __ATOMIC_RELAXED, __HIP_MEMORY_SCOPE_AGENT);
        while (__hip_atomic_load(cnt, __ATOMIC_RELAXED, __HIP_MEMORY_SCOPE_AGENT) < NBLK)
            __builtin_amdgcn_s_sleep(8);
    }
    __syncthreads();

    // ---- phase 2: dst nodes i = 2b, 2b+1; coalesced relaxed row loads
    #pragma unroll
    for (int ii = 0; ii < IPB; ++ii) {
        const int i = blockIdx.x * IPB + ii;
        const float v = __hip_atomic_load(feat_t + i * FEATS + t,
                                          __ATOMIC_RELAXED, __HIP_MEMORY_SCOPE_AGENT);
        #pragma unroll
        for (int o = 0; o < NOUT; ++o) {
            float p = v * G[o];
            #pragma unroll
            for (int off = 32; off; off >>= 1) p += __shfl_xor(p, off);
            if (lane == 0) part[o][wid] = p;
        }
        __syncthreads();
        if (t < NOUT) {
            float sacc = cst[t];
            #pragma unroll
            for (int w = 0; w < 8; ++w) sacc += part[t][w];
            out[i * NOUT + t] = 1.f / (1.f + __builtin_amdgcn_exp2f(-sacc * LOG2E));
        }
        __syncthreads();                  // part reuse
    }
}

// ---------------- Fallback: fused O(N^3) kernel (if ws too small) ----------------
__global__ __launch_bounds__(512) void gat_fused_fb(
    const float* __restrict__ data,
    const float* __restrict__ gat_w, const float* __restrict__ a_src,
    const float* __restrict__ a_dst, const float* __restrict__ gat_bias,
    const float* __restrict__ F1, const float* __restrict__ fb1,
    const float* __restrict__ F2, const float* __restrict__ fb2,
    float* __restrict__ out)
{
    __shared__ __align__(16) float xs[FEATS];
    __shared__ float feat[FEATS];
    __shared__ float part[NH][8];
    __shared__ float hv[NH];
    const int h = threadIdx.x;
    const int i = blockIdx.x;
    float v = 0.f;
    #pragma unroll
    for (int w = 0; w < NW; ++w) v += data[w * FEATS + h];
    xs[h] = v;
    __syncthreads();
    const float LOG2E = 1.4426950408889634f;
    const float gwv = gat_w[h];
    const float cs = gwv * a_src[h] * LOG2E;
    const float cd = gwv * a_dst[h] * LOG2E;
    const float di = xs[i] * cd;
    float se = 0.f, sv = 0.f;
    const float4* x4 = (const float4*)xs;
    for (int j4 = 0; j4 < FEATS / 4; ++j4) {
        float4 q = x4[j4];
        #pragma unroll
        for (int u = 0; u < 4; ++u) {
            float xj = (u == 0) ? q.x : (u == 1) ? q.y : (u == 2) ? q.z : q.w;
            float tt = fmaf(xj, cs, di);
            float l  = fmaxf(tt, 0.2f * tt);
            float e  = __builtin_amdgcn_exp2f(l);
            se += e;
            sv = fmaf(e, xj, sv);
        }
    }
    feat[h] = gwv * sv / se + gat_bias[h];
    __syncthreads();
    const int lane = h & 63, wid = h >> 6;
    const float fv = feat[h];
    for (int k = 0; k < NH; ++k) {
        float p = fv * F1[k * FEATS + h];
        #pragma unroll
        for (int off = 32; off; off >>= 1) p += __shfl_xor(p, off);
        if (lane == 0) part[k][wid] = p;
    }
    __syncthreads();
    if (h < NH) {
        float s = fb1[h];
        #pragma unroll
        for (int w = 0; w < 8; ++w) s += part[h][w];
        hv[h] = s;
    }
    __syncthreads();
    if (h < 5) {
        float s = fb2[h];
        #pragma unroll
        for (int k = 0; k < NH; ++k) s = fmaf(hv[k], F2[h * NH + k], s);
        out[i * 5 + h] = 1.f / (1.f + __builtin_amdgcn_exp2f(-s * LOG2E));
    }
}

extern "C" void kernel_launch(void* const* d_in, const int* in_sizes, int n_in,
                              void* d_out, int out_size, void* d_ws, size_t ws_size,
                              hipStream_t stream) {
    (void)in_sizes; (void)n_in; (void)out_size;
    const float* data     = (const float*)d_in[0];
    // d_in[1..6] = W1,b1,W2,b2,W3,b3 — dead (softmax over batch dim of size 1 == 1)
    const float* gat_w    = (const float*)d_in[7];
    const float* a_src    = (const float*)d_in[8];
    const float* a_dst    = (const float*)d_in[9];
    const float* gat_bias = (const float*)d_in[10];
    const float* F1       = (const float*)d_in[11];
    const float* fb1      = (const float*)d_in[12];
    const float* F2       = (const float*)d_in[13];
    const float* fb2      = (const float*)d_in[14];
    float* out = (float*)d_out;

    if (ws_size >= (size_t)WS_FLOATS_NEEDED * sizeof(float)) {
        float* ws = (float*)d_ws;
        prep_sort<<<64, FEATS, 0, stream>>>(data, ws);
        gat_barrier<<<NBLK, FEATS, 0, stream>>>(ws, gat_w, a_src, a_dst, gat_bias,
                                                F1, fb1, F2, fb2, out);
    } else {
        gat_fused_fb<<<FEATS, FEATS, 0, stream>>>(data, gat_w, a_src, a_dst, gat_bias,
                                                  F1, fb1, F2, fb2, out);
    }
}